// Round 6
// baseline (160.022 us; speedup 1.0000x reference)
//
#include <hip/hip_runtime.h>

#define WW 1280
#define HH 720
#define NB 8
#define NPIX (HH * WW)            // 921600
#define TOTAL (NB * NPIX)         // 7372800

#define FMAX 4.0f                 // |flow| < 4 -> inlier (corners within +/-4)
#define RHALO 4
#define TH 16                     // 720 = 45*16
#define TW 64                     // 1280 = 20*64
#define TPIX (TH * TW)            // 1024 -> 16KB LDS (4 arrays)
#define TILES_X (WW / TW)         // 20
#define TILES_Y (HH / TH)         // 45
#define TPB (TILES_X * TILES_Y)   // 900
#define NT (NB * TPB)             // 7200 (divisible by 8)
#define WH (TH + 2 * RHALO)       // 24
#define WWIN (TW + 2 * RHALO)     // 72
#define GPR (WWIN / 4)            // 18 float4-groups per window row
#define NGRP (WH * GPR)           // 432
#define NITER 2                   // ceil(NGRP/256)
#define CAPB 4096                 // per-batch outlier capacity (expect ~120)

// ---------------------------------------------------------------------------
// K1: build per-batch outlier lists (valid target but |fx|>=4 or |fy|>=4).
// Entry = {pixel, fx_bits, fy_bits, depth_bits} so K2 never reloads them.
// ---------------------------------------------------------------------------
__global__ void k1_outliers(const float* __restrict__ flow,
                            const float* __restrict__ depth,
                            int* __restrict__ nOut, int4* __restrict__ lists) {
    int i = blockIdx.x * blockDim.x + threadIdx.x;      // one float4 group
    int p4 = i * 4;
    int b = p4 / NPIX;
    int p = p4 - b * NPIX;
    int y = p / WW;
    int x0 = p - y * WW;
    const float* fb = flow + (size_t)b * 2 * NPIX;
    float4 fx4 = *(const float4*)&fb[p];
    float4 fy4 = *(const float4*)&fb[p + NPIX];
    float fxs[4] = {fx4.x, fx4.y, fx4.z, fx4.w};
    float fys[4] = {fy4.x, fy4.y, fy4.z, fy4.w};
#pragma unroll
    for (int j = 0; j < 4; ++j) {
        float fx = fxs[j], fy = fys[j];
        if (fabsf(fx) < FMAX && fabsf(fy) < FMAX) continue;          // inlier
        float x2 = (float)(x0 + j) + fx, y2 = (float)y + fy;
        if (!(x2 >= 0.f && y2 >= 0.f && x2 <= (float)(WW - 1) && y2 <= (float)(HH - 1)))
            continue;                                                 // invalid
        float d = depth[(size_t)b * NPIX + p + j];
        int pos = atomicAdd(&nOut[b], 1);
        if (pos < CAPB)
            lists[b * CAPB + pos] =
                make_int4(p + j, __float_as_int(fx), __float_as_int(fy), __float_as_int(d));
    }
}

// ---------------------------------------------------------------------------
// K2: per-tile gather, single window scan. Phase A loads window (float4),
// captures fx/fy/db + packed corner geometry in registers, LDS atomicMin.
// Phase B replays from registers (zero global loads, minimal decode) doing
// gated LDS adds. Outliers merged from per-batch lists. Divide + store tile.
// Packed format: bit31 = valid; bits13..9 = lyT+8; bits8..2 = lxL+8;
// bit1 = xR clamped (==xL); bit0 = yB clamped (==yT).
// ---------------------------------------------------------------------------
__global__ void __launch_bounds__(256, 8)
k2_gather(const float* __restrict__ flow, const float* __restrict__ depth,
          const int* __restrict__ nOut, const int4* __restrict__ lists,
          float* __restrict__ out) {
    __shared__ int   mind_t[TPIX];
    __shared__ float sx_t[TPIX];
    __shared__ float sy_t[TPIX];
    __shared__ float cn_t[TPIX];

    int bid = blockIdx.x;
    { const int c = NT >> 3; bid = (bid & 7) * c + (bid >> 3); }  // XCD swizzle
    const int b   = bid / TPB;
    const int tt  = bid - b * TPB;
    const int tty = tt / TILES_X;
    const int ty0 = tty * TH;
    const int tx0 = (tt - tty * TILES_X) * TW;
    const int tid = threadIdx.x;
    const float* flowb  = flow  + (size_t)b * 2 * NPIX;
    const float* depthb = depth + (size_t)b * NPIX;

    {   // vectorized init: one float4 per array per thread (TPIX == 256*4)
        int k4 = tid * 4;
        const int IB = __float_as_int(1e30f);
        *(int4*)&mind_t[k4] = make_int4(IB, IB, IB, IB);
        float4 z = make_float4(0.f, 0.f, 0.f, 0.f);
        *(float4*)&sx_t[k4] = z;
        *(float4*)&sy_t[k4] = z;
        *(float4*)&cn_t[k4] = z;
    }
    __syncthreads();

    // ---- phase A: window scan (float4 groups), capture regs, LDS min ----
    float    fxA[NITER * 4], fyA[NITER * 4];
    int      dbA[NITER * 4];
    unsigned pkA[NITER * 4];
#pragma unroll
    for (int it = 0; it < NITER; ++it) {
        int g   = tid + it * 256;
        int wy  = g / GPR;
        int gx0 = tx0 - RHALO + (g - wy * GPR) * 4;
        int gy  = ty0 - RHALO + wy;
#pragma unroll
        for (int j = 0; j < 4; ++j) pkA[it * 4 + j] = 0u;
        if (g >= NGRP || (unsigned)gy >= HH || (unsigned)gx0 >= WW) continue;
        int p = gy * WW + gx0;
        float4 a = *(const float4*)&flowb[p];
        float4 c = *(const float4*)&flowb[p + NPIX];
        float4 d = *(const float4*)&depthb[p];
        float fxs[4] = {a.x, a.y, a.z, a.w};
        float fys[4] = {c.x, c.y, c.z, c.w};
        float ds[4]  = {d.x, d.y, d.z, d.w};
#pragma unroll
        for (int j = 0; j < 4; ++j) {
            int q = it * 4 + j;
            float fx = fxs[j], fy = fys[j];
            fxA[q] = fx; fyA[q] = fy; dbA[q] = __float_as_int(ds[j]);
            if (!(fabsf(fx) < FMAX && fabsf(fy) < FMAX)) continue;
            float x2 = (float)(gx0 + j) + fx, y2 = (float)gy + fy;
            if (!(x2 >= 0.f && y2 >= 0.f && x2 <= (float)(WW - 1) && y2 <= (float)(HH - 1)))
                continue;
            int xL = (int)floorf(x2), yT = (int)floorf(y2);   // >=0 given validity
            int xR = min(xL + 1, WW - 1), yB = min(yT + 1, HH - 1);
            int cR = (xR == xL), cB = (yB == yT);
            int lxL = xL - tx0, lyT = yT - ty0;
            int lxR = lxL + (cR ^ 1), lyB = lyT + (cB ^ 1);
            pkA[q] = 0x80000000u | (unsigned)((lyT + 8) << 9) |
                     (unsigned)((lxL + 8) << 2) | (unsigned)(cR << 1) | (unsigned)cB;
            int db = dbA[q];
            if ((unsigned)lyT < TH) {
                if ((unsigned)lxL < TW) atomicMin(&mind_t[lyT * TW + lxL], db);
                if ((unsigned)lxR < TW) atomicMin(&mind_t[lyT * TW + lxR], db);
            }
            if ((unsigned)lyB < TH) {
                if ((unsigned)lxL < TW) atomicMin(&mind_t[lyB * TW + lxL], db);
                if ((unsigned)lxR < TW) atomicMin(&mind_t[lyB * TW + lxR], db);
            }
        }
    }
    // ---- outlier mins (per-batch list, self-contained entries) ----
    const int nb = min(nOut[b], CAPB);
    for (int j = tid; j < nb; j += 256) {
        int4 e = lists[b * CAPB + j];
        float fx = __int_as_float(e.y), fy = __int_as_float(e.z);
        int y = e.x / WW, x = e.x - y * WW;
        float x2 = (float)x + fx, y2 = (float)y + fy;
        int xL = min(max((int)floorf(x2), 0), WW - 1);
        int yT = min(max((int)floorf(y2), 0), HH - 1);
        int xR = min(xL + 1, WW - 1), yB = min(yT + 1, HH - 1);
        int lxL = xL - tx0, lxR = xR - tx0, lyT = yT - ty0, lyB = yB - ty0;
        if ((unsigned)lyT < TH) {
            if ((unsigned)lxL < TW) atomicMin(&mind_t[lyT * TW + lxL], e.w);
            if ((unsigned)lxR < TW) atomicMin(&mind_t[lyT * TW + lxR], e.w);
        }
        if ((unsigned)lyB < TH) {
            if ((unsigned)lxL < TW) atomicMin(&mind_t[lyB * TW + lxL], e.w);
            if ((unsigned)lxR < TW) atomicMin(&mind_t[lyB * TW + lxR], e.w);
        }
    }
    __syncthreads();

    // ---- phase B: replay from registers (packed geometry), gated LDS adds ----
#pragma unroll
    for (int it = 0; it < NITER; ++it) {
#pragma unroll
        for (int j = 0; j < 4; ++j) {
            int q = it * 4 + j;
            unsigned pk = pkA[q];
            if (!(pk >> 31)) continue;
            int lxL = (int)((pk >> 2) & 0x7Fu) - 8;
            int lyT = (int)((pk >> 9) & 0x1Fu) - 8;
            int lxR = lxL + 1 - (int)((pk >> 1) & 1u);
            int lyB = lyT + 1 - (int)(pk & 1u);
            float fx = fxA[q], fy = fyA[q];
            int db = dbA[q];
            int ls[4] = {
                ((unsigned)lyT < TH && (unsigned)lxL < TW) ? lyT * TW + lxL : -1,
                ((unsigned)lyT < TH && (unsigned)lxR < TW) ? lyT * TW + lxR : -1,
                ((unsigned)lyB < TH && (unsigned)lxL < TW) ? lyB * TW + lxL : -1,
                ((unsigned)lyB < TH && (unsigned)lxR < TW) ? lyB * TW + lxR : -1 };
#pragma unroll
            for (int c = 0; c < 4; ++c) {
                int l = ls[c];
                if (l >= 0 && mind_t[l] == db) {
                    atomicAdd(&sx_t[l], -fx);
                    atomicAdd(&sy_t[l], -fy);
                    atomicAdd(&cn_t[l], 1.0f);
                }
            }
        }
    }
    // ---- outlier adds ----
    for (int j = tid; j < nb; j += 256) {
        int4 e = lists[b * CAPB + j];
        float fx = __int_as_float(e.y), fy = __int_as_float(e.z);
        int y = e.x / WW, x = e.x - y * WW;
        float x2 = (float)x + fx, y2 = (float)y + fy;
        int xL = min(max((int)floorf(x2), 0), WW - 1);
        int yT = min(max((int)floorf(y2), 0), HH - 1);
        int xR = min(xL + 1, WW - 1), yB = min(yT + 1, HH - 1);
        int lxL = xL - tx0, lxR = xR - tx0, lyT = yT - ty0, lyB = yB - ty0;
        int ls[4] = {
            ((unsigned)lyT < TH && (unsigned)lxL < TW) ? lyT * TW + lxL : -1,
            ((unsigned)lyT < TH && (unsigned)lxR < TW) ? lyT * TW + lxR : -1,
            ((unsigned)lyB < TH && (unsigned)lxL < TW) ? lyB * TW + lxL : -1,
            ((unsigned)lyB < TH && (unsigned)lxR < TW) ? lyB * TW + lxR : -1 };
#pragma unroll
        for (int c = 0; c < 4; ++c) {
            int l = ls[c];
            if (l >= 0 && mind_t[l] == e.w) {
                atomicAdd(&sx_t[l], -fx);
                atomicAdd(&sy_t[l], -fy);
                atomicAdd(&cn_t[l], 1.0f);
            }
        }
    }
    __syncthreads();

    // ---- epilogue: divide + float4 store of the owned tile ----
    {
        int k4 = tid * 4;
        int ly = k4 >> 6;          // /TW
        int lx = k4 & 63;
        float4 s4 = *(float4*)&sx_t[k4];
        float4 t4 = *(float4*)&sy_t[k4];
        float4 c4 = *(float4*)&cn_t[k4];
        float4 ox, oy;
        ox.x = (c4.x > 0.f) ? s4.x / c4.x : 0.f;  oy.x = (c4.x > 0.f) ? t4.x / c4.x : 0.f;
        ox.y = (c4.y > 0.f) ? s4.y / c4.y : 0.f;  oy.y = (c4.y > 0.f) ? t4.y / c4.y : 0.f;
        ox.z = (c4.z > 0.f) ? s4.z / c4.z : 0.f;  oy.z = (c4.z > 0.f) ? t4.z / c4.z : 0.f;
        ox.w = (c4.w > 0.f) ? s4.w / c4.w : 0.f;  oy.w = (c4.w > 0.f) ? t4.w / c4.w : 0.f;
        size_t o = (size_t)b * 2 * NPIX + (size_t)(ty0 + ly) * WW + (tx0 + lx);
        *(float4*)&out[o]        = ox;
        *(float4*)&out[o + NPIX] = oy;
    }
}

extern "C" void kernel_launch(void* const* d_in, const int* in_sizes, int n_in,
                              void* d_out, int out_size, void* d_ws, size_t ws_size,
                              hipStream_t stream) {
    const float* flow  = (const float*)d_in[0];
    const float* depth = (const float*)d_in[1];
    float* out = (float*)d_out;

    int*  nOut  = (int*)d_ws;                 // 16 ints (first NB used)
    int4* lists = (int4*)((char*)d_ws + 64);  // NB * CAPB entries

    hipMemsetAsync(nOut, 0, 64, stream);
    k1_outliers<<<TOTAL / 4 / 256, 256, 0, stream>>>(flow, depth, nOut, lists);
    k2_gather  <<<NT, 256, 0, stream>>>(flow, depth, nOut, lists, out);
}

// Round 7
// 159.694 us; speedup vs baseline: 1.0021x; 1.0021x over previous
//
#include <hip/hip_runtime.h>

#define WW 1280
#define HH 720
#define NB 8
#define NPIX (HH * WW)            // 921600
#define TOTAL (NB * NPIX)         // 7372800

#define FMAX 4.0f                 // |flow| < 4 -> inlier (corners within +/-4)
#define RHALO 4
#define TH 16                     // 720 = 45*16
#define TW 64                     // 1280 = 20*64
#define TPIX (TH * TW)            // 1024 -> 16KB LDS (4 arrays)
#define TILES_X (WW / TW)         // 20
#define TILES_Y (HH / TH)         // 45
#define TPB (TILES_X * TILES_Y)   // 900
#define NT (NB * TPB)             // 7200 (divisible by 8)
#define WH (TH + 2 * RHALO)       // 24
#define WWIN (TW + 2 * RHALO)     // 72
#define WPOS (WH * WWIN)          // 1728 scalar window positions
#define NITER 7                   // ceil(WPOS/256)
#define CAPB 4096                 // per-batch outlier capacity (expect ~120)

// ---------------------------------------------------------------------------
// K1: build per-batch outlier lists (valid target but |fx|>=4 or |fy|>=4).
// Entry = {pixel, fx_bits, fy_bits, depth_bits} so K2 never reloads them.
// ---------------------------------------------------------------------------
__global__ void k1_outliers(const float* __restrict__ flow,
                            const float* __restrict__ depth,
                            int* __restrict__ nOut, int4* __restrict__ lists) {
    int i = blockIdx.x * blockDim.x + threadIdx.x;      // one float4 group
    int p4 = i * 4;
    int b = p4 / NPIX;
    int p = p4 - b * NPIX;
    int y = p / WW;
    int x0 = p - y * WW;
    const float* fb = flow + (size_t)b * 2 * NPIX;
    float4 fx4 = *(const float4*)&fb[p];
    float4 fy4 = *(const float4*)&fb[p + NPIX];
    float fxs[4] = {fx4.x, fx4.y, fx4.z, fx4.w};
    float fys[4] = {fy4.x, fy4.y, fy4.z, fy4.w};
#pragma unroll
    for (int j = 0; j < 4; ++j) {
        float fx = fxs[j], fy = fys[j];
        if (fabsf(fx) < FMAX && fabsf(fy) < FMAX) continue;          // inlier
        float x2 = (float)(x0 + j) + fx, y2 = (float)y + fy;
        if (!(x2 >= 0.f && y2 >= 0.f && x2 <= (float)(WW - 1) && y2 <= (float)(HH - 1)))
            continue;                                                 // invalid
        float d = depth[(size_t)b * NPIX + p + j];
        int pos = atomicAdd(&nOut[b], 1);
        if (pos < CAPB)
            lists[b * CAPB + pos] =
                make_int4(p + j, __float_as_int(fx), __float_as_int(fy), __float_as_int(d));
    }
}

// ---------------------------------------------------------------------------
// K2: per-tile gather, single window scan, SCALAR 1px/lane mapping so that
// consecutive lanes process consecutive x -> LDS corner addresses are
// ~stride-1 across the wave -> ~2 lanes/bank (free) instead of the float4
// grouping's stride-4 (8-way conflict).
// Phase A: load + capture {fx,fy,db,packed-geometry} in regs + LDS atomicMin.
// Phase B: replay from regs, gated LDS adds. Outliers from per-batch lists.
// Packed format: bit31 = valid; bits13..9 = lyT+8; bits8..2 = lxL+8;
// bit1 = xR clamped (==xL); bit0 = yB clamped (==yT).
// ---------------------------------------------------------------------------
__global__ void __launch_bounds__(256, 8)
k2_gather(const float* __restrict__ flow, const float* __restrict__ depth,
          const int* __restrict__ nOut, const int4* __restrict__ lists,
          float* __restrict__ out) {
    __shared__ int   mind_t[TPIX];
    __shared__ float sx_t[TPIX];
    __shared__ float sy_t[TPIX];
    __shared__ float cn_t[TPIX];

    int bid = blockIdx.x;
    { const int c = NT >> 3; bid = (bid & 7) * c + (bid >> 3); }  // XCD swizzle
    const int b   = bid / TPB;
    const int tt  = bid - b * TPB;
    const int tty = tt / TILES_X;
    const int ty0 = tty * TH;
    const int tx0 = (tt - tty * TILES_X) * TW;
    const int tid = threadIdx.x;
    const float* flowb  = flow  + (size_t)b * 2 * NPIX;
    const float* depthb = depth + (size_t)b * NPIX;

    {   // vectorized init: one float4 per array per thread (TPIX == 256*4)
        int k4 = tid * 4;
        const int IB = __float_as_int(1e30f);
        *(int4*)&mind_t[k4] = make_int4(IB, IB, IB, IB);
        float4 z = make_float4(0.f, 0.f, 0.f, 0.f);
        *(float4*)&sx_t[k4] = z;
        *(float4*)&sy_t[k4] = z;
        *(float4*)&cn_t[k4] = z;
    }
    __syncthreads();

    // ---- phase A: scalar window scan, capture regs, LDS min ----
    float    fxA[NITER], fyA[NITER];
    int      dbA[NITER];
    unsigned pkA[NITER];
#pragma unroll
    for (int it = 0; it < NITER; ++it) {
        pkA[it] = 0u;
        int s  = tid + it * 256;
        int wy = s / WWIN;
        int wx = s - wy * WWIN;
        int gy = ty0 - RHALO + wy;
        int gx = tx0 - RHALO + wx;
        if (s >= WPOS || (unsigned)gy >= HH || (unsigned)gx >= WW) continue;
        int p = gy * WW + gx;
        float fx = flowb[p];
        float fy = flowb[p + NPIX];
        float d  = depthb[p];
        fxA[it] = fx; fyA[it] = fy;
        int db = __float_as_int(d);
        dbA[it] = db;
        if (!(fabsf(fx) < FMAX && fabsf(fy) < FMAX)) continue;
        float x2 = (float)gx + fx, y2 = (float)gy + fy;
        if (!(x2 >= 0.f && y2 >= 0.f && x2 <= (float)(WW - 1) && y2 <= (float)(HH - 1)))
            continue;
        int xL = (int)floorf(x2), yT = (int)floorf(y2);   // >=0 given validity
        int xR = min(xL + 1, WW - 1), yB = min(yT + 1, HH - 1);
        int cR = (xR == xL), cB = (yB == yT);
        int lxL = xL - tx0, lyT = yT - ty0;
        int lxR = lxL + (cR ^ 1), lyB = lyT + (cB ^ 1);
        pkA[it] = 0x80000000u | (unsigned)((lyT + 8) << 9) |
                  (unsigned)((lxL + 8) << 2) | (unsigned)(cR << 1) | (unsigned)cB;
        if ((unsigned)lyT < TH) {
            if ((unsigned)lxL < TW) atomicMin(&mind_t[lyT * TW + lxL], db);
            if ((unsigned)lxR < TW) atomicMin(&mind_t[lyT * TW + lxR], db);
        }
        if ((unsigned)lyB < TH) {
            if ((unsigned)lxL < TW) atomicMin(&mind_t[lyB * TW + lxL], db);
            if ((unsigned)lxR < TW) atomicMin(&mind_t[lyB * TW + lxR], db);
        }
    }
    // ---- outlier mins (per-batch list, self-contained entries) ----
    const int nb = min(nOut[b], CAPB);
    for (int j = tid; j < nb; j += 256) {
        int4 e = lists[b * CAPB + j];
        float fx = __int_as_float(e.y), fy = __int_as_float(e.z);
        int y = e.x / WW, x = e.x - y * WW;
        float x2 = (float)x + fx, y2 = (float)y + fy;
        int xL = min(max((int)floorf(x2), 0), WW - 1);
        int yT = min(max((int)floorf(y2), 0), HH - 1);
        int xR = min(xL + 1, WW - 1), yB = min(yT + 1, HH - 1);
        int lxL = xL - tx0, lxR = xR - tx0, lyT = yT - ty0, lyB = yB - ty0;
        if ((unsigned)lyT < TH) {
            if ((unsigned)lxL < TW) atomicMin(&mind_t[lyT * TW + lxL], e.w);
            if ((unsigned)lxR < TW) atomicMin(&mind_t[lyT * TW + lxR], e.w);
        }
        if ((unsigned)lyB < TH) {
            if ((unsigned)lxL < TW) atomicMin(&mind_t[lyB * TW + lxL], e.w);
            if ((unsigned)lxR < TW) atomicMin(&mind_t[lyB * TW + lxR], e.w);
        }
    }
    __syncthreads();

    // ---- phase B: replay from registers (packed geometry), gated LDS adds ----
#pragma unroll
    for (int it = 0; it < NITER; ++it) {
        unsigned pk = pkA[it];
        if (!(pk >> 31)) continue;
        int lxL = (int)((pk >> 2) & 0x7Fu) - 8;
        int lyT = (int)((pk >> 9) & 0x1Fu) - 8;
        int lxR = lxL + 1 - (int)((pk >> 1) & 1u);
        int lyB = lyT + 1 - (int)(pk & 1u);
        float fx = fxA[it], fy = fyA[it];
        int db = dbA[it];
        int ls[4] = {
            ((unsigned)lyT < TH && (unsigned)lxL < TW) ? lyT * TW + lxL : -1,
            ((unsigned)lyT < TH && (unsigned)lxR < TW) ? lyT * TW + lxR : -1,
            ((unsigned)lyB < TH && (unsigned)lxL < TW) ? lyB * TW + lxL : -1,
            ((unsigned)lyB < TH && (unsigned)lxR < TW) ? lyB * TW + lxR : -1 };
#pragma unroll
        for (int c = 0; c < 4; ++c) {
            int l = ls[c];
            if (l >= 0 && mind_t[l] == db) {
                atomicAdd(&sx_t[l], -fx);
                atomicAdd(&sy_t[l], -fy);
                atomicAdd(&cn_t[l], 1.0f);
            }
        }
    }
    // ---- outlier adds ----
    for (int j = tid; j < nb; j += 256) {
        int4 e = lists[b * CAPB + j];
        float fx = __int_as_float(e.y), fy = __int_as_float(e.z);
        int y = e.x / WW, x = e.x - y * WW;
        float x2 = (float)x + fx, y2 = (float)y + fy;
        int xL = min(max((int)floorf(x2), 0), WW - 1);
        int yT = min(max((int)floorf(y2), 0), HH - 1);
        int xR = min(xL + 1, WW - 1), yB = min(yT + 1, HH - 1);
        int lxL = xL - tx0, lxR = xR - tx0, lyT = yT - ty0, lyB = yB - ty0;
        int ls[4] = {
            ((unsigned)lyT < TH && (unsigned)lxL < TW) ? lyT * TW + lxL : -1,
            ((unsigned)lyT < TH && (unsigned)lxR < TW) ? lyT * TW + lxR : -1,
            ((unsigned)lyB < TH && (unsigned)lxL < TW) ? lyB * TW + lxL : -1,
            ((unsigned)lyB < TH && (unsigned)lxR < TW) ? lyB * TW + lxR : -1 };
#pragma unroll
        for (int c = 0; c < 4; ++c) {
            int l = ls[c];
            if (l >= 0 && mind_t[l] == e.w) {
                atomicAdd(&sx_t[l], -fx);
                atomicAdd(&sy_t[l], -fy);
                atomicAdd(&cn_t[l], 1.0f);
            }
        }
    }
    __syncthreads();

    // ---- epilogue: divide + float4 store of the owned tile ----
    {
        int k4 = tid * 4;
        int ly = k4 >> 6;          // /TW
        int lx = k4 & 63;
        float4 s4 = *(float4*)&sx_t[k4];
        float4 t4 = *(float4*)&sy_t[k4];
        float4 c4 = *(float4*)&cn_t[k4];
        float4 ox, oy;
        ox.x = (c4.x > 0.f) ? s4.x / c4.x : 0.f;  oy.x = (c4.x > 0.f) ? t4.x / c4.x : 0.f;
        ox.y = (c4.y > 0.f) ? s4.y / c4.y : 0.f;  oy.y = (c4.y > 0.f) ? t4.y / c4.y : 0.f;
        ox.z = (c4.z > 0.f) ? s4.z / c4.z : 0.f;  oy.z = (c4.z > 0.f) ? t4.z / c4.z : 0.f;
        ox.w = (c4.w > 0.f) ? s4.w / c4.w : 0.f;  oy.w = (c4.w > 0.f) ? t4.w / c4.w : 0.f;
        size_t o = (size_t)b * 2 * NPIX + (size_t)(ty0 + ly) * WW + (tx0 + lx);
        *(float4*)&out[o]        = ox;
        *(float4*)&out[o + NPIX] = oy;
    }
}

extern "C" void kernel_launch(void* const* d_in, const int* in_sizes, int n_in,
                              void* d_out, int out_size, void* d_ws, size_t ws_size,
                              hipStream_t stream) {
    const float* flow  = (const float*)d_in[0];
    const float* depth = (const float*)d_in[1];
    float* out = (float*)d_out;

    int*  nOut  = (int*)d_ws;                 // 16 ints (first NB used)
    int4* lists = (int4*)((char*)d_ws + 64);  // NB * CAPB entries

    hipMemsetAsync(nOut, 0, 64, stream);
    k1_outliers<<<TOTAL / 4 / 256, 256, 0, stream>>>(flow, depth, nOut, lists);
    k2_gather  <<<NT, 256, 0, stream>>>(flow, depth, nOut, lists, out);
}